// Round 12
// baseline (232.350 us; speedup 1.0000x reference)
//
#include <hip/hip_runtime.h>
#include <cstdint>

// BasisFunction1D: out[o,b] = sum_i (1-d)*P[idx,o,i] + d*P[idx+1,o,i]
//
// R18 = R10 (best measured: 92.6us total, main_k ~38us warm) with ONE change:
//   the divergent ds_read_b128 gather is split into TWO ds_read_b64 from
//   SEPARATE LDS regions (slabL = o{0,1}, slabR = o{2,3}, 16KB apart so the
//   compiler cannot re-fuse into b128 or ds_read2).
//   Rationale: SQ_LDS_BANK_CONFLICT is data-invariant (3.65M every round);
//   main_k is pinned at 38-52us across all schedule variants. Competing
//   models: 19cy/gather (counter) vs ~40cy (m136 8-way scaling for 64
//   unique 16B rows over 8 bank-quads). Random b64 = 64 lanes over 16
//   bank-pair slots (~4-way, 1.58x) -> if b128-divergent is pathological,
//   2xb64 ~= 20-24cy vs ~40. This round changes instruction shape only;
//   schedule, occupancy, traffic identical to R10.

#define NG 128
#define NI 128
#define NO 128
#define NB 8192
#define WO 4
#define PH 8

using half2v  = __attribute__((ext_vector_type(2))) _Float16;
using float4v = __attribute__((ext_vector_type(4))) float;

__device__ inline uint32_t pack_f16x2(float lo, float hi) {
    _Float16 hl = (_Float16)lo, hh = (_Float16)hi;
    return (uint32_t)__builtin_bit_cast(unsigned short, hl) |
           ((uint32_t)__builtin_bit_cast(unsigned short, hh) << 16);
}

// ---- K1: P[g,o,i] -> Q2[((s*NI+i)*NG+g)*4+ow] = pack(P, dP), o=s*4+ow ----
// (proven R10 version: 64B-contiguous stores)
__global__ __launch_bounds__(256) void build_q(const float* __restrict__ P,
                                               uint32_t* __restrict__ Q2) {
    __shared__ float L[5][16][128];             // 40 KB
    const int gb = blockIdx.x >> 3;
    const int ob = blockIdx.x & 7;
    const int g0 = gb * 4;
    const int o0 = ob * 16;
    const int s0 = ob * 4;
    const int t  = threadIdx.x;
    #pragma unroll
    for (int pass = 0; pass < 40; ++pass) {     // 80 rows x 128 i
        int row = pass * 2 + (t >> 7);
        int i   = t & 127;
        int gg  = row >> 4, ol = row & 15;
        L[gg][ol][i] = P[(size_t)(g0 + gg) * (NO * NI) + (o0 + ol) * NI + i];
    }
    __syncthreads();
    #pragma unroll
    for (int pp = 0; pp < 2; ++pp) {
        int item = pp * 256 + t;                // 4 sl x 128 i
        int i  = item & 127;
        int sl = item >> 7;
        uint32_t* dst = Q2 + ((size_t)((s0 + sl) * NI + i) * NG + g0) * 4;
        #pragma unroll
        for (int gg = 0; gg < 4; ++gg) {
            uint32_t r[4];
            #pragma unroll
            for (int ow = 0; ow < 4; ++ow) {
                float pl = L[gg][sl * 4 + ow][i];
                float dd = L[gg + 1][sl * 4 + ow][i] - pl;
                r[ow] = pack_f16x2(pl, dd);
            }
            *(uint4*)(dst + gg * 4) = make_uint4(r[0], r[1], r[2], r[3]);
        }
    }
}

// ---- K2: bucketize x -> T[i][b] = (idx*16) | (f16(d) << 16) ----
__global__ __launch_bounds__(256) void build_t(const float* __restrict__ x,
                                               const float* __restrict__ borders,
                                               const float* __restrict__ icl,
                                               uint32_t* __restrict__ T) {
    const int e0 = (blockIdx.x * 256 + threadIdx.x) * 4;
    const float4 xv = *(const float4*)(x + e0);
    uint32_t r[4];
    const float xs[4] = {xv.x, xv.y, xv.z, xv.w};
    #pragma unroll
    for (int k = 0; k < 4; ++k) {
        float v = xs[k];
        float ea = __expf(-fabsf(v));
        float cdf = v > 0.f ? 1.f - 0.5f * ea : 0.5f * ea;
        int idx = (int)(cdf * 128.f);
        idx = idx > 127 ? 127 : idx;
        float d = (v - borders[idx]) * icl[idx];
        _Float16 hd = (_Float16)d;
        r[k] = ((uint32_t)idx << 4) |
               ((uint32_t)__builtin_bit_cast(unsigned short, hd) << 16);
    }
    *(uint4*)(T + e0) = make_uint4(r[0], r[1], r[2], r[3]);
}

// ---- K3: main. 1024 thr; 1024 b x 4 o x 64 i; 2 blocks/CU; split gather --
__global__ __launch_bounds__(1024, 8) void main_k(const uint32_t* __restrict__ Q2,
                                                  const uint32_t* __restrict__ T,
                                                  float* __restrict__ part) {
    __shared__ uint32_t slabL[2][PH][NG * 2];   // 16 KB: o{0,1} halves
    __shared__ uint32_t slabR[2][PH][NG * 2];   // 16 KB: o{2,3} halves
    const int t    = threadIdx.x;
    const int bx   = blockIdx.x;
    const int s    = bx & 31;                   // o-slice (4 o); same-s blocks
    const int ih   = (bx >> 5) & 1;             //   share one XCD (bx%8==s%8)
    const int bblk = (bx >> 6) << 10;           // b-tile of 1024
    const int bme  = bblk + t;                  // lane's batch
    const uint32_t* Qs = Q2 + ((size_t)s * NI + ih * 64) * (NG * WO);
    const uint32_t* Ts = T + (size_t)(ih * 64) * NB;

    float a0 = 0.f, a1 = 0.f, a2 = 0.f, a3 = 0.f;

    // prologue: stage phase 0 (16 KB; each thread 16B -> 8B L + 8B R)
    uint32_t treg[PH];
    {
        uint4 q0 = *(const uint4*)(Qs + (size_t)t * 4);
        #pragma unroll
        for (int il = 0; il < PH; ++il)
            treg[il] = Ts[(size_t)il * NB + bme];
        ((uint2*)&slabL[0][0][0])[t] = make_uint2(q0.x, q0.y);
        ((uint2*)&slabR[0][0][0])[t] = make_uint2(q0.z, q0.w);
    }
    __syncthreads();

    #pragma unroll
    for (int p = 0; p < 8; ++p) {
        const int cur = p & 1;
        uint32_t tnxt[PH];
        uint4 qnxt;
        if (p < 7) {
            qnxt = *(const uint4*)(Qs + (size_t)(p + 1) * (PH * NG * WO) +
                                   (size_t)t * 4);
            #pragma unroll
            for (int il = 0; il < PH; ++il)
                tnxt[il] = Ts[(size_t)((p + 1) * PH + il) * NB + bme];
        }
        #pragma unroll
        for (int il = 0; il < PH; ++il) {
            uint32_t tw   = treg[il];
            uint32_t offL = (tw & 0xFFFFu) >> 1;            // idx*8 bytes
            uint32_t w2b  = (tw & 0xFFFF0000u) | 0x3C00u;   // {1.0h, d}
            uint2 qa = *(const uint2*)((const char*)&slabL[cur][il][0] + offL);
            uint2 qb = *(const uint2*)((const char*)&slabR[cur][il][0] + offL);
            half2v w2 = __builtin_bit_cast(half2v, w2b);
            a0 = __builtin_amdgcn_fdot2(__builtin_bit_cast(half2v, qa.x), w2, a0, false);
            a1 = __builtin_amdgcn_fdot2(__builtin_bit_cast(half2v, qa.y), w2, a1, false);
            a2 = __builtin_amdgcn_fdot2(__builtin_bit_cast(half2v, qb.x), w2, a2, false);
            a3 = __builtin_amdgcn_fdot2(__builtin_bit_cast(half2v, qb.y), w2, a3, false);
        }
        if (p < 7) {
            ((uint2*)&slabL[cur ^ 1][0][0])[t] = make_uint2(qnxt.x, qnxt.y);
            ((uint2*)&slabR[cur ^ 1][0][0])[t] = make_uint2(qnxt.z, qnxt.w);
            #pragma unroll
            for (int il = 0; il < PH; ++il)
                treg[il] = tnxt[il];
            __syncthreads();
        }
    }

    // partial store: part[ih][o][b]; 1024-lane contiguous 4KB runs per o
    float* po = part + (size_t)ih * (NO * NB) + (size_t)(s * 4) * NB + bme;
    po[0]              = a0;
    po[NB]             = a1;
    po[2 * (size_t)NB] = a2;
    po[3 * (size_t)NB] = a3;
}

// ---- K4: out = part0 + part1 (1M floats) ----
__global__ __launch_bounds__(256) void reduce_k(const float* __restrict__ part,
                                                float* __restrict__ out) {
    const int e0 = (blockIdx.x * 256 + threadIdx.x) * 4;
    const float4v v0 = *(const float4v*)(part + e0);
    const float4v v1 = *(const float4v*)(part + (size_t)NO * NB + e0);
    const float4v r  = v0 + v1;
    __builtin_nontemporal_store(r, (float4v*)(out + e0));
}

extern "C" void kernel_launch(void* const* d_in, const int* in_sizes, int n_in,
                              void* d_out, int out_size, void* d_ws, size_t ws_size,
                              hipStream_t stream) {
    const float* x       = (const float*)d_in[0];
    const float* P       = (const float*)d_in[1];
    const float* borders = (const float*)d_in[2];
    const float* icl     = (const float*)d_in[3];
    float* out = (float*)d_out;

    uint32_t* Q2  = (uint32_t*)d_ws;                 // 8 MB
    uint32_t* T   = Q2 + (size_t)NO * NI * NG;       // 4 MB
    float*    prt = (float*)(T + (size_t)NI * NB);   // 8 MB (two halves)

    hipLaunchKernelGGL(build_q, dim3(256), dim3(256), 0, stream, P, Q2);
    hipLaunchKernelGGL(build_t, dim3(NI * NB / 1024), dim3(256), 0, stream,
                       x, borders, icl, T);
    hipLaunchKernelGGL(main_k, dim3(512), dim3(1024), 0, stream, Q2, T, prt);
    hipLaunchKernelGGL(reduce_k, dim3(NO * NB / 1024), dim3(256), 0, stream,
                       prt, out);
}

// Round 13
// 93.509 us; speedup vs baseline: 2.4848x; 2.4848x over previous
//
#include <hip/hip_runtime.h>
#include <cstdint>

// BasisFunction1D: out[o,b] = sum_i (1-d)*P[idx,o,i] + d*P[idx+1,o,i]
//
// R19 = R10 (best measured, 92.6us) with build_q+build_t FUSED (one launch).
//   R18 resolved the main_k model: divergent-gather conflict cost is
//   per-instruction shape-invariant (2xb64 doubled SQ_LDS_BANK_CONFLICT);
//   main_k is ~85% LDS-gather-pipe-bound at ~35-40cy/wave-gather -> its
//   38us is within ~15% of that floor; 8 schedule variants plateau there.
//   Remaining slack is aux: fuse the two build kernels (memory-bound,
//   disjoint block ranges) to save a launch gap + overlap their BW.
//   main_k and reduce_k are byte-identical to R10.

#define NG 128
#define NI 128
#define NO 128
#define NB 8192
#define WO 4
#define PH 8

using half2v  = __attribute__((ext_vector_type(2))) _Float16;
using float4v = __attribute__((ext_vector_type(4))) float;

__device__ inline uint32_t pack_f16x2(float lo, float hi) {
    _Float16 hl = (_Float16)lo, hh = (_Float16)hi;
    return (uint32_t)__builtin_bit_cast(unsigned short, hl) |
           ((uint32_t)__builtin_bit_cast(unsigned short, hh) << 16);
}

// ---- K1 (fused): blocks 0..255 -> Q2 pack; 256..1279 -> T bucketize ------
// Q2[((s*NI+i)*NG+g)*4+ow] = pack(P[g,o,i], P[g+1,o,i]-P[g,o,i]), o=s*4+ow.
// T[i][b] = (idx*16) | (f16(d)<<16).
__global__ __launch_bounds__(256) void build_k(const float* __restrict__ P,
                                               const float* __restrict__ x,
                                               const float* __restrict__ borders,
                                               const float* __restrict__ icl,
                                               uint32_t* __restrict__ Q2,
                                               uint32_t* __restrict__ T) {
    const int t = threadIdx.x;
    if (blockIdx.x < 256) {
        // ---- build_q body (proven R10 version: 64B-contiguous stores) ----
        __shared__ float L[5][16][128];         // 40 KB
        const int gb = blockIdx.x >> 3;
        const int ob = blockIdx.x & 7;
        const int g0 = gb * 4;
        const int o0 = ob * 16;
        const int s0 = ob * 4;
        #pragma unroll
        for (int pass = 0; pass < 40; ++pass) { // 80 rows x 128 i
            int row = pass * 2 + (t >> 7);
            int i   = t & 127;
            int gg  = row >> 4, ol = row & 15;
            L[gg][ol][i] = P[(size_t)(g0 + gg) * (NO * NI) + (o0 + ol) * NI + i];
        }
        __syncthreads();
        #pragma unroll
        for (int pp = 0; pp < 2; ++pp) {
            int item = pp * 256 + t;            // 4 sl x 128 i
            int i  = item & 127;
            int sl = item >> 7;
            uint32_t* dst = Q2 + ((size_t)((s0 + sl) * NI + i) * NG + g0) * 4;
            #pragma unroll
            for (int gg = 0; gg < 4; ++gg) {
                uint32_t r[4];
                #pragma unroll
                for (int ow = 0; ow < 4; ++ow) {
                    float pl = L[gg][sl * 4 + ow][i];
                    float dd = L[gg + 1][sl * 4 + ow][i] - pl;
                    r[ow] = pack_f16x2(pl, dd);
                }
                *(uint4*)(dst + gg * 4) = make_uint4(r[0], r[1], r[2], r[3]);
            }
        }
    } else {
        // ---- build_t body (proven R6/R10 version: coalesced T[i][b]) -----
        const int e0 = ((blockIdx.x - 256) * 256 + t) * 4;
        const float4 xv = *(const float4*)(x + e0);
        uint32_t r[4];
        const float xs[4] = {xv.x, xv.y, xv.z, xv.w};
        #pragma unroll
        for (int k = 0; k < 4; ++k) {
            float v = xs[k];
            float ea = __expf(-fabsf(v));
            float cdf = v > 0.f ? 1.f - 0.5f * ea : 0.5f * ea;
            int idx = (int)(cdf * 128.f);
            idx = idx > 127 ? 127 : idx;
            float d = (v - borders[idx]) * icl[idx];
            _Float16 hd = (_Float16)d;
            r[k] = ((uint32_t)idx << 4) |
                   ((uint32_t)__builtin_bit_cast(unsigned short, hd) << 16);
        }
        *(uint4*)(T + e0) = make_uint4(r[0], r[1], r[2], r[3]);
    }
}

// ---- K2: main. 1024 thr; 1024 b x 4 o x 64 i per block; 2 blocks/CU ----
// (byte-identical to R10's main_k: best measured, warm ~38us)
__global__ __launch_bounds__(1024, 8) void main_k(const uint32_t* __restrict__ Q2,
                                                  const uint32_t* __restrict__ T,
                                                  float* __restrict__ part) {
    __shared__ uint32_t slab[2][PH][NG * WO];   // 32 KB
    const int t    = threadIdx.x;
    const int bx   = blockIdx.x;
    const int s    = bx & 31;                   // o-slice (4 o); same-s blocks
    const int ih   = (bx >> 5) & 1;             //   share one XCD (bx%8==s%8)
    const int bblk = (bx >> 6) << 10;           // b-tile of 1024
    const int bme  = bblk + t;                  // lane's batch
    const uint32_t* Qs = Q2 + ((size_t)s * NI + ih * 64) * (NG * WO);
    const uint32_t* Ts = T + (size_t)(ih * 64) * NB;

    float a0 = 0.f, a1 = 0.f, a2 = 0.f, a3 = 0.f;

    // prologue: stage phase 0 (16 KB; each thread 16B) + 8 T words
    uint32_t treg[PH];
    {
        uint4 q0 = *(const uint4*)(Qs + (size_t)t * 4);
        #pragma unroll
        for (int il = 0; il < PH; ++il)
            treg[il] = Ts[(size_t)il * NB + bme];
        ((uint4*)&slab[0][0][0])[t] = q0;
    }
    __syncthreads();

    #pragma unroll
    for (int p = 0; p < 8; ++p) {
        const int cur = p & 1;
        uint32_t tnxt[PH];
        uint4 qnxt;
        if (p < 7) {
            qnxt = *(const uint4*)(Qs + (size_t)(p + 1) * (PH * NG * WO) +
                                   (size_t)t * 4);
            #pragma unroll
            for (int il = 0; il < PH; ++il)
                tnxt[il] = Ts[(size_t)((p + 1) * PH + il) * NB + bme];
        }
        #pragma unroll
        for (int il = 0; il < PH; ++il) {
            uint32_t tw  = treg[il];
            uint32_t off = tw & 0xFFFFu;                    // idx*16 bytes
            uint32_t w2b = (tw & 0xFFFF0000u) | 0x3C00u;    // {1.0h, d}
            uint4 q = *(const uint4*)((const char*)&slab[cur][il][0] + off);
            half2v w2 = __builtin_bit_cast(half2v, w2b);
            a0 = __builtin_amdgcn_fdot2(__builtin_bit_cast(half2v, q.x), w2, a0, false);
            a1 = __builtin_amdgcn_fdot2(__builtin_bit_cast(half2v, q.y), w2, a1, false);
            a2 = __builtin_amdgcn_fdot2(__builtin_bit_cast(half2v, q.z), w2, a2, false);
            a3 = __builtin_amdgcn_fdot2(__builtin_bit_cast(half2v, q.w), w2, a3, false);
        }
        if (p < 7) {
            ((uint4*)&slab[cur ^ 1][0][0])[t] = qnxt;
            #pragma unroll
            for (int il = 0; il < PH; ++il)
                treg[il] = tnxt[il];
            __syncthreads();
        }
    }

    // partial store: part[ih][o][b]; 1024-lane contiguous 4KB runs per o
    float* po = part + (size_t)ih * (NO * NB) + (size_t)(s * 4) * NB + bme;
    __builtin_nontemporal_store(a0, po);
    __builtin_nontemporal_store(a1, po + NB);
    __builtin_nontemporal_store(a2, po + 2 * (size_t)NB);
    __builtin_nontemporal_store(a3, po + 3 * (size_t)NB);
}

// ---- K3: out = part0 + part1 (1M floats) ----
__global__ __launch_bounds__(256) void reduce_k(const float* __restrict__ part,
                                                float* __restrict__ out) {
    const int e0 = (blockIdx.x * 256 + threadIdx.x) * 4;
    const float4v v0 = *(const float4v*)(part + e0);
    const float4v v1 = *(const float4v*)(part + (size_t)NO * NB + e0);
    const float4v r  = v0 + v1;
    __builtin_nontemporal_store(r, (float4v*)(out + e0));
}

extern "C" void kernel_launch(void* const* d_in, const int* in_sizes, int n_in,
                              void* d_out, int out_size, void* d_ws, size_t ws_size,
                              hipStream_t stream) {
    const float* x       = (const float*)d_in[0];
    const float* P       = (const float*)d_in[1];
    const float* borders = (const float*)d_in[2];
    const float* icl     = (const float*)d_in[3];
    float* out = (float*)d_out;

    uint32_t* Q2  = (uint32_t*)d_ws;                 // 8 MB
    uint32_t* T   = Q2 + (size_t)NO * NI * NG;       // 4 MB
    float*    prt = (float*)(T + (size_t)NI * NB);   // 8 MB (two halves)

    hipLaunchKernelGGL(build_k, dim3(1280), dim3(256), 0, stream,
                       P, x, borders, icl, Q2, T);
    hipLaunchKernelGGL(main_k, dim3(512), dim3(1024), 0, stream, Q2, T, prt);
    hipLaunchKernelGGL(reduce_k, dim3(NO * NB / 1024), dim3(256), 0, stream,
                       prt, out);
}